// Round 4
// baseline (869.312 us; speedup 1.0000x reference)
//
#include <hip/hip_runtime.h>
#include <hip/hip_bf16.h>

// GCN forward. dinv folded into GEMM epilogue => weightless u16 CSR.
//   h'[r]    = dinv[r] * (x_l @ W_l)[r]          (gemm epilogue scale)
//   x_{l+1}[c] = dinv[c]*(sum_{e:src->c} h'[src] + h'[c]) + b_l
// Bucketed fixed-capacity CSR (no global scan, no degree prepass).
// n = 50001, D = 128, E = 800000, 3 layers. fp32 in/out, bf16 internal.
//
// Pull is XCD-slice-partitioned WITH HARDWARE PINNING: h is slice-major
// h[8][NPAD][16] (1.6 MB per slice). k_pull is persistent (2048 blocks);
// each block reads its physical XCD id (s_getreg HW_REG_XCC_ID) and drains
// a per-slice atomic chunk queue, so XCD s only gathers slice s -> the
// slice table is guaranteed L2-resident irrespective of dispatch order.
// After its own queue drains, a block steals from other slices (correctness
// never depends on XCC_ID values, only locality does).

constexpr int NN     = 50001;
constexpr int D      = 128;
constexpr int NPAD   = 50048;        // 391 * 128 rows (gemm grid)
constexpr int NBK    = 196;          // ceil(NN/256) dst buckets
constexpr int CAP    = 7680;         // per-bucket capacity incl. pad-to-16
constexpr int ZROW   = NPAD - 1;     // guaranteed-zero h row for meta padding
constexpr int NCHUNK = NPAD / 128;   // 391 node-chunks per slice

using bf16x8 = __attribute__((ext_vector_type(8))) short;
using f32x4  = __attribute__((ext_vector_type(4))) float;
using f32x2  = __attribute__((ext_vector_type(2))) float;
using u16x8  = __attribute__((ext_vector_type(8))) unsigned short;
using u32x4  = __attribute__((ext_vector_type(4))) unsigned;

__device__ __forceinline__ ushort f2b(float f) {         // fp32 -> bf16 RNE
    unsigned u = __float_as_uint(f);
    return (ushort)((u + 0x7FFFu + ((u >> 16) & 1u)) >> 16);
}
__device__ __forceinline__ float b2f(ushort u) {
    return __uint_as_float((unsigned)u << 16);
}

// ---------------- build: partition edges + Wt convert + xb0 init (one kernel) ----------------
__global__ __launch_bounds__(256)
void k_build(const int* __restrict__ row, const int* __restrict__ col,
             int* __restrict__ partCur, unsigned* __restrict__ part,
             const float* __restrict__ W, ushort* __restrict__ Wt,
             const float* __restrict__ emb, ushort* __restrict__ xb, int E, int n) {
    int b = blockIdx.x, t = threadIdx.x;
    if (b < NBK) {
        __shared__ int hist[256];
        __shared__ int base[256];
        hist[t] = 0;
        __syncthreads();
        int e0 = b * 4096;
        unsigned rec[16];
        int bkt[16];
#pragma unroll
        for (int k = 0; k < 16; k++) {
            int e = e0 + k * 256 + t;
            if (e < E) {
                int r = row[e], c = col[e];
                rec[k] = (unsigned)r | ((unsigned)(c & 255) << 16);
                bkt[k] = c >> 8;
                atomicAdd(&hist[bkt[k]], 1);
            } else bkt[k] = -1;
        }
        __syncthreads();
        if (hist[t] > 0) base[t] = t * CAP + atomicAdd(&partCur[t], hist[t]);
        __syncthreads();
#pragma unroll
        for (int k = 0; k < 16; k++) {
            if (bkt[k] >= 0) {
                int pos = atomicAdd(&base[bkt[k]], 1);
                if (pos < (bkt[k] + 1) * CAP) part[pos] = rec[k];   // overflow guard
            }
        }
    } else if (b < NBK + 192) {
        int idx = (b - NBK) * 256 + t;               // [0, 3*128*128)
        int l = idx >> 14, rem = idx & 16383;
        int c = rem >> 7, k = rem & 127;
        Wt[idx] = f2b(W[l * D * D + k * D + c]);
    } else {
        int i4 = (b - NBK - 192) * 256 + t;          // float4 groups
        if (i4 >= NPAD * (D / 4)) return;
        int r = i4 >> 5;
        if (r < n) {
            float4 v = ((const float4*)emb)[i4];
            ushort4 o; o.x = f2b(v.x); o.y = f2b(v.y); o.z = f2b(v.z); o.w = f2b(v.w);
            ((ushort4*)xb)[i4] = o;
        } else {
            ((ushort4*)xb)[i4] = make_ushort4(0, 0, 0, 0);
        }
    }
}

// ---------------- scat: per bucket histogram -> dinv + packed rp + permuted u16 meta ----------------
// rp[node] = {metaStart:21 | deg:11}; meta bucket-major, per-node segment padded to 16
// (pad entries = ZROW, a guaranteed-zero h row) so pull does tail-free 16-edge chunks.
__global__ __launch_bounds__(256)
void k_scat(const unsigned* __restrict__ part, const int* __restrict__ partCur,
            float* __restrict__ dinv, unsigned* __restrict__ rp,
            ushort* __restrict__ meta, int n) {
    __shared__ int hist[256];
    __shared__ int sm[256];
    __shared__ int off[256];
    __shared__ int cur[256];
    int b = blockIdx.x, t = threadIdx.x;
    int node0 = b * 256;
    int nn = min(256, n - node0);
    int T = min(partCur[b], CAP);
    const unsigned* pb = part + (size_t)b * CAP;
    hist[t] = 0;
    __syncthreads();
    for (int i = t; i < T; i += 256) atomicAdd(&hist[pb[i] >> 16], 1);
    __syncthreads();
    int v = hist[t];
    int pv = (v + 15) & ~15;                         // pad segment to 16 entries
    sm[t] = pv;
    __syncthreads();
    for (int ofs = 1; ofs < 256; ofs <<= 1) {        // inclusive scan of padded sizes
        int u = (t >= ofs) ? sm[t - ofs] : 0;
        __syncthreads();
        sm[t] += u;
        __syncthreads();
    }
    off[t] = sm[t] - pv;                             // exclusive, 16-aligned
    cur[t] = 0;
    if (t < nn) {
        dinv[node0 + t] = rsqrtf((float)v + 1.0f);   // +1 self loop
        rp[node0 + t] = (unsigned)(b * CAP + off[t]) | ((unsigned)v << 21);
    }
    __syncthreads();
    for (int i = t; i < T; i += 256) {
        unsigned rec = pb[i];
        int dl = (int)(rec >> 16);
        int pos = off[dl] + atomicAdd(&cur[dl], 1);
        if (pos < CAP) meta[(size_t)b * CAP + pos] = (ushort)(rec & 0xFFFFu);
    }
    int base = off[t];
    for (int p = v; p < pv; p++)                     // fill pad slots with zero row
        if (base + p < CAP) meta[(size_t)b * CAP + base + p] = (ushort)ZROW;
}

// ---------------- MFMA GEMM: h[8][NPAD][16] = dinv[row] * (xb @ W), bf16, slice-major ----------------
// Column block ct IS the slice index. Pad rows [n, NPAD) stored with dv=0 -> h rows of
// ZROW are zero in every slice (pull pads gather them).
constexpr int WT_LD = 136;   // padded LDS row stride (shorts)
__global__ __launch_bounds__(256)
void k_gemm_mfma(const ushort* __restrict__ xb, const ushort* __restrict__ WtL,
                 const float* __restrict__ dinv, ushort* __restrict__ h, int n) {
    __shared__ ushort wlds[D * WT_LD];
    for (int idx = threadIdx.x; idx < D * (D / 8); idx += 256) {
        int r = idx >> 4, c8 = (idx & 15) * 8;
        *(uint4*)&wlds[r * WT_LD + c8] = *(const uint4*)&WtL[r * D + c8];
    }
    __syncthreads();

    int wave = threadIdx.x >> 6, lane = threadIdx.x & 63;
    int q = lane >> 4, i = lane & 15;
    int waveRow = blockIdx.x * 128 + wave * 32;

    bf16x8 a[2][4];
#pragma unroll
    for (int rt = 0; rt < 2; rt++) {
        const ushort* base = &xb[(size_t)(waveRow + rt * 16 + i) * D + q * 8];
#pragma unroll
        for (int ks = 0; ks < 4; ks++)
            a[rt][ks] = *(const bf16x8*)(base + ks * 32);
    }

    f32x4 acc[2][8] = {};
#pragma unroll
    for (int ct = 0; ct < 8; ct++) {
        const ushort* wbase = &wlds[(ct * 16 + i) * WT_LD + q * 8];
#pragma unroll
        for (int ks = 0; ks < 4; ks++) {
            bf16x8 bfr = *(const bf16x8*)(wbase + ks * 32);
            acc[0][ct] = __builtin_amdgcn_mfma_f32_16x16x32_bf16(a[0][ks], bfr, acc[0][ct], 0, 0, 0);
            acc[1][ct] = __builtin_amdgcn_mfma_f32_16x16x32_bf16(a[1][ks], bfr, acc[1][ct], 0, 0, 0);
        }
    }

#pragma unroll
    for (int rt = 0; rt < 2; rt++)
#pragma unroll
        for (int r4 = 0; r4 < 4; r4++) {
            int row = waveRow + rt * 16 + q * 4 + r4;
            float dv = (row < n) ? dinv[row] : 0.f;   // pad rows -> 0 (ZROW guarantee)
#pragma unroll
            for (int ct = 0; ct < 8; ct++)            // slice-major store: slice = ct
                h[(size_t)ct * ((size_t)NPAD * 16) + (size_t)row * 16 + i] =
                    f2b(acc[rt][ct][r4] * dv);
        }
}

// ---------------- pull aggregation (persistent, XCD-pinned slices) ----------------
// 2048 blocks; block reads its physical XCD id and drains per-slice chunk queue wq[8]
// (391 chunks x 128 nodes). 2 lanes/node, lane owns 8 features (16 B gathers) of the
// slice. Meta padded to 16 with ZROW -> tail-free 16-edge bursts, issued before
// accumulate. After own slice drains, block steals from other slices (coverage is
// guaranteed even if XCC_ID were constant).
// acc = h'[node] + sum h'[src]; result = acc*dinv[node] + bias.
// mode 0: write bf16 x_{l+1} (zero pad rows). mode 1: out = emb + x1 + x2 + x3.
__global__ __launch_bounds__(256)
void k_pull(const unsigned* __restrict__ rp, const ushort* __restrict__ meta,
            const ushort* __restrict__ h,
            const float* __restrict__ dinv, const float* __restrict__ bias,
            ushort* __restrict__ xb_out,
            const float* __restrict__ emb, const ushort* __restrict__ x1,
            const ushort* __restrict__ x2, float* __restrict__ out,
            int* __restrict__ wq, int n, int mode) {
    int xcc;
    asm volatile("s_getreg_b32 %0, hwreg(HW_REG_XCC_ID)" : "=s"(xcc));
    int myslice = xcc & 7;
    int tid = threadIdx.x;
    int l   = tid & 1;                                // which 8-feature half of slice
    __shared__ int sh_chunk;

    for (int so = 0; so < 8; so++) {
        int slice = (myslice + so) & 7;
        int f0 = slice * 16 + l * 8;                  // first feature this thread owns
        const ushort* hs = h + (size_t)slice * ((size_t)NPAD * 16) + l * 8;
        const float4* bp = (const float4*)(bias + f0);
        float4 b0 = bp[0], b1 = bp[1];

        for (;;) {
            __syncthreads();
            if (tid == 0) sh_chunk = atomicAdd(wq + slice, 1);
            __syncthreads();
            int c = sh_chunk;
            if (c >= NCHUNK) break;                   // uniform

            int node = c * 128 + (tid >> 1);
            size_t o = (size_t)node * D + f0;
            if (node >= n) {                          // pad rows [n, NPAD)
                if (mode == 0) {
                    u16x8 z = {0, 0, 0, 0, 0, 0, 0, 0};
                    *(u16x8*)(xb_out + o) = z;
                }
                continue;
            }
            unsigned pk = rp[node];
            int s   = (int)(pk & 0x1FFFFFu);
            int deg = (int)(pk >> 21);

            // early issue: epilogue streams ride under gather latency
            u32x4 sv = *(const u32x4*)(hs + (size_t)node * 16);   // self loop
            float di = dinv[node];
            float4 e0, e1; u16x8 w1, w2;
            if (mode) {
                const float4* ep = (const float4*)(emb + o);
                e0 = ep[0]; e1 = ep[1];
                w1 = *(const u16x8*)(x1 + o);
                w2 = *(const u16x8*)(x2 + o);
            }

            float accL[4], accH[4];                   // accL[k]=feat 2k, accH[k]=feat 2k+1
#pragma unroll
            for (int k = 0; k < 4; k++) {
                accL[k] = __uint_as_float(sv[k] << 16);
                accH[k] = __uint_as_float(sv[k] & 0xFFFF0000u);
            }

            for (int j = 0; j < deg; j += 16) {
                u16x8 m0 = *(const u16x8*)&meta[s + j];
                u16x8 m1 = *(const u16x8*)&meta[s + j + 8];
                u32x4 v[16];
#pragma unroll
                for (int u = 0; u < 8; u++) v[u]     = *(const u32x4*)(hs + (size_t)m0[u] * 16);
#pragma unroll
                for (int u = 0; u < 8; u++) v[8 + u] = *(const u32x4*)(hs + (size_t)m1[u] * 16);
#pragma unroll
                for (int u = 0; u < 16; u++)
#pragma unroll
                    for (int k = 0; k < 4; k++) {
                        accL[k] += __uint_as_float(v[u][k] << 16);
                        accH[k] += __uint_as_float(v[u][k] & 0xFFFF0000u);
                    }
            }

            float r0 = fmaf(accL[0], di, b0.x);
            float r1 = fmaf(accH[0], di, b0.y);
            float r2 = fmaf(accL[1], di, b0.z);
            float r3 = fmaf(accH[1], di, b0.w);
            float r4 = fmaf(accL[2], di, b1.x);
            float r5 = fmaf(accH[2], di, b1.y);
            float r6 = fmaf(accL[3], di, b1.z);
            float r7 = fmaf(accH[3], di, b1.w);
            if (mode == 0) {
                u16x8 w;
                w[0] = f2b(r0); w[1] = f2b(r1); w[2] = f2b(r2); w[3] = f2b(r3);
                w[4] = f2b(r4); w[5] = f2b(r5); w[6] = f2b(r6); w[7] = f2b(r7);
                *(u16x8*)(xb_out + o) = w;
            } else {
                f32x4 o0, o1;
                o0[0] = e0.x + b2f(w1[0]) + b2f(w2[0]) + r0;
                o0[1] = e0.y + b2f(w1[1]) + b2f(w2[1]) + r1;
                o0[2] = e0.z + b2f(w1[2]) + b2f(w2[2]) + r2;
                o0[3] = e0.w + b2f(w1[3]) + b2f(w2[3]) + r3;
                o1[0] = e1.x + b2f(w1[4]) + b2f(w2[4]) + r4;
                o1[1] = e1.y + b2f(w1[5]) + b2f(w2[5]) + r5;
                o1[2] = e1.z + b2f(w1[6]) + b2f(w2[6]) + r6;
                o1[3] = e1.w + b2f(w1[7]) + b2f(w2[7]) + r7;
                __builtin_nontemporal_store(o0, (f32x4*)(out + o));
                __builtin_nontemporal_store(o1, (f32x4*)(out + o) + 1);
            }
        }
    }
}

extern "C" void kernel_launch(void* const* d_in, const int* in_sizes, int n_in,
                              void* d_out, int out_size, void* d_ws, size_t ws_size,
                              hipStream_t stream) {
    const int*   edge = (const int*)d_in[0];    // [2, E]
    const float* emb  = (const float*)d_in[1];  // [100001, 128]
    const float* W    = (const float*)d_in[2];  // [3, 128, 128]
    const float* b    = (const float*)d_in[3];  // [3, 128]
    float* out = (float*)d_out;                 // [50001, 128] fp32

    const int E = in_sizes[0] / 2;
    const int n = NN;
    const int* row = edge;
    const int* col = edge + E;

    char* ws = (char*)d_ws;
    size_t off = 0;
    auto carve = [&](size_t bytes) { char* p = ws + off; off = (off + bytes + 511) / 512 * 512; return p; };
    int*      partCur = (int*)     carve(256 * 4);
    int*      workCtr = (int*)     carve(3 * 8 * 4);               // per-layer slice queues
    unsigned* part    = (unsigned*)carve((size_t)NBK * CAP * 4);   // 6.0 MB
    ushort*   meta    = (ushort*)  carve((size_t)NBK * CAP * 2);   // 3.0 MB
    unsigned* rp      = (unsigned*)carve((size_t)n * 4);
    float*    dinv    = (float*)   carve((size_t)n * 4);
    ushort*   Wt      = (ushort*)  carve((size_t)3 * D * D * 2);
    ushort*   xb0     = (ushort*)  carve((size_t)NPAD * D * 2);
    ushort*   xb1     = (ushort*)  carve((size_t)NPAD * D * 2);
    ushort*   xb2     = (ushort*)  carve((size_t)NPAD * D * 2);
    ushort*   h       = (ushort*)  carve((size_t)NPAD * D * 2);    // slice-major [8][NPAD][16]

    // one small memset covers partCur (1024 B) + workCtr (96 B, contiguous carve)
    (void)hipMemsetAsync(partCur, 0, 1024 + 512, stream);

    const int init_blocks  = (NPAD * (D / 4) + 255) / 256;   // 6256
    const int build_blocks = NBK + 192 + init_blocks;        // 6644
    k_build<<<build_blocks, 256, 0, stream>>>(row, col, partCur, part, W, Wt, emb, xb0, E, n);
    k_scat <<<NBK, 256, 0, stream>>>(part, partCur, dinv, rp, meta, n);

    const int gemm_blocks = NPAD / 128;          // 391
    const int pull_blocks = 2048;                // persistent, ~8 blocks/CU
    ushort* xin[3]  = {xb0, xb1, xb2};
    ushort* xout[3] = {xb1, xb2, nullptr};
    for (int l = 0; l < 3; l++) {
        k_gemm_mfma<<<gemm_blocks, 256, 0, stream>>>(xin[l], Wt + (size_t)l * D * D, dinv, h, n);
        k_pull<<<pull_blocks, 256, 0, stream>>>(rp, meta, h,
                                                dinv, b + (size_t)l * D, xout[l],
                                                emb, xb1, xb2, out,
                                                workCtr + l * 8, n, (l < 2) ? 0 : 1);
    }
}

// Round 5
// 238.998 us; speedup vs baseline: 3.6373x; 3.6373x over previous
//
#include <hip/hip_runtime.h>
#include <hip/hip_bf16.h>

// GCN forward. dinv folded into GEMM epilogue => weightless u16 CSR.
//   h'[r]    = dinv[r] * (x_l @ W_l)[r]          (gemm epilogue scale)
//   x_{l+1}[c] = dinv[c]*(sum_{e:src->c} h'[src] + h'[c]) + b_l
// Bucketed fixed-capacity CSR (no global scan, no degree prepass).
// n = 50001, D = 128, E = 800000, 3 layers. fp32 in/out, bf16 internal.
//
// Structure: build -> scat -> gemm0 -> F1(pull0+gemm1) -> F2(pull1+gemm2)
// -> pull_final. The fused F kernel: one block = 16 dst nodes; 16 lanes/node
// aggregate (16B gathers, full 256B coalesced rows, 16-edge ZROW-padded
// bursts), x-tile lands in LDS, then the same block runs the 16x128 MFMA
// GEMM for the NEXT layer (B-frags streamed from L2-resident Wt). This
// removes 2 GEMM dispatches, 2 launch gaps, and the xb write->read
// round-trip, and overlaps MFMA with other blocks' gathers.

constexpr int NN   = 50001;
constexpr int D    = 128;
constexpr int NPAD = 50048;          // 3128 * 16 rows
constexpr int NBK  = 196;            // ceil(NN/256) dst buckets
constexpr int CAP  = 7680;           // per-bucket capacity incl. pad-to-16
constexpr int ZROW = NPAD - 1;       // guaranteed-zero h row for meta padding

using bf16x8 = __attribute__((ext_vector_type(8))) short;
using f32x4  = __attribute__((ext_vector_type(4))) float;
using u16x8  = __attribute__((ext_vector_type(8))) unsigned short;
using u32x4  = __attribute__((ext_vector_type(4))) unsigned;

__device__ __forceinline__ ushort f2b(float f) {         // fp32 -> bf16 RNE
    unsigned u = __float_as_uint(f);
    return (ushort)((u + 0x7FFFu + ((u >> 16) & 1u)) >> 16);
}
__device__ __forceinline__ float b2f(ushort u) {
    return __uint_as_float((unsigned)u << 16);
}

// ---------------- build: partition edges + Wt convert + xb0 init (one kernel) ----------------
__global__ __launch_bounds__(256)
void k_build(const int* __restrict__ row, const int* __restrict__ col,
             int* __restrict__ partCur, unsigned* __restrict__ part,
             const float* __restrict__ W, ushort* __restrict__ Wt,
             const float* __restrict__ emb, ushort* __restrict__ xb, int E, int n) {
    int b = blockIdx.x, t = threadIdx.x;
    if (b < NBK) {
        __shared__ int hist[256];
        __shared__ int base[256];
        hist[t] = 0;
        __syncthreads();
        int e0 = b * 4096;
        unsigned rec[16];
        int bkt[16];
#pragma unroll
        for (int k = 0; k < 16; k++) {
            int e = e0 + k * 256 + t;
            if (e < E) {
                int r = row[e], c = col[e];
                rec[k] = (unsigned)r | ((unsigned)(c & 255) << 16);
                bkt[k] = c >> 8;
                atomicAdd(&hist[bkt[k]], 1);
            } else bkt[k] = -1;
        }
        __syncthreads();
        if (hist[t] > 0) base[t] = t * CAP + atomicAdd(&partCur[t], hist[t]);
        __syncthreads();
#pragma unroll
        for (int k = 0; k < 16; k++) {
            if (bkt[k] >= 0) {
                int pos = atomicAdd(&base[bkt[k]], 1);
                if (pos < (bkt[k] + 1) * CAP) part[pos] = rec[k];   // overflow guard
            }
        }
    } else if (b < NBK + 192) {
        int idx = (b - NBK) * 256 + t;               // [0, 3*128*128)
        int l = idx >> 14, rem = idx & 16383;
        int c = rem >> 7, k = rem & 127;
        Wt[idx] = f2b(W[l * D * D + k * D + c]);
    } else {
        int i4 = (b - NBK - 192) * 256 + t;          // float4 groups
        if (i4 >= NPAD * (D / 4)) return;
        int r = i4 >> 5;
        if (r < n) {
            float4 v = ((const float4*)emb)[i4];
            ushort4 o; o.x = f2b(v.x); o.y = f2b(v.y); o.z = f2b(v.z); o.w = f2b(v.w);
            ((ushort4*)xb)[i4] = o;
        } else {
            ((ushort4*)xb)[i4] = make_ushort4(0, 0, 0, 0);
        }
    }
}

// ---------------- scat: per bucket histogram -> dinv + packed rp + permuted u16 meta ----------------
// rp[node] = {metaStart:21 | deg:11}; meta bucket-major, per-node segment padded to 16
// (pad entries = ZROW, a guaranteed-zero h row) so pull does tail-free 16-edge chunks.
__global__ __launch_bounds__(256)
void k_scat(const unsigned* __restrict__ part, const int* __restrict__ partCur,
            float* __restrict__ dinv, unsigned* __restrict__ rp,
            ushort* __restrict__ meta, int n) {
    __shared__ int hist[256];
    __shared__ int sm[256];
    __shared__ int off[256];
    __shared__ int cur[256];
    int b = blockIdx.x, t = threadIdx.x;
    int node0 = b * 256;
    int nn = min(256, n - node0);
    int T = min(partCur[b], CAP);
    const unsigned* pb = part + (size_t)b * CAP;
    hist[t] = 0;
    __syncthreads();
    for (int i = t; i < T; i += 256) atomicAdd(&hist[pb[i] >> 16], 1);
    __syncthreads();
    int v = hist[t];
    int pv = (v + 15) & ~15;                         // pad segment to 16 entries
    sm[t] = pv;
    __syncthreads();
    for (int ofs = 1; ofs < 256; ofs <<= 1) {        // inclusive scan of padded sizes
        int u = (t >= ofs) ? sm[t - ofs] : 0;
        __syncthreads();
        sm[t] += u;
        __syncthreads();
    }
    off[t] = sm[t] - pv;                             // exclusive, 16-aligned
    cur[t] = 0;
    if (t < nn) {
        dinv[node0 + t] = rsqrtf((float)v + 1.0f);   // +1 self loop
        rp[node0 + t] = (unsigned)(b * CAP + off[t]) | ((unsigned)v << 21);
    }
    __syncthreads();
    for (int i = t; i < T; i += 256) {
        unsigned rec = pb[i];
        int dl = (int)(rec >> 16);
        int pos = off[dl] + atomicAdd(&cur[dl], 1);
        if (pos < CAP) meta[(size_t)b * CAP + pos] = (ushort)(rec & 0xFFFFu);
    }
    int base = off[t];
    for (int p = v; p < pv; p++)                     // fill pad slots with zero row
        if (base + p < CAP) meta[(size_t)b * CAP + base + p] = (ushort)ZROW;
}

// ---------------- MFMA GEMM (layer 0 only): h[NPAD,128] = dinv[row] * (xb @ W) ----------------
constexpr int WT_LD = 136;   // padded LDS row stride (shorts)
__global__ __launch_bounds__(256)
void k_gemm_mfma(const ushort* __restrict__ xb, const ushort* __restrict__ WtL,
                 const float* __restrict__ dinv, ushort* __restrict__ h, int n) {
    __shared__ ushort wlds[D * WT_LD];
    for (int idx = threadIdx.x; idx < D * (D / 8); idx += 256) {
        int r = idx >> 4, c8 = (idx & 15) * 8;
        *(uint4*)&wlds[r * WT_LD + c8] = *(const uint4*)&WtL[r * D + c8];
    }
    __syncthreads();

    int wave = threadIdx.x >> 6, lane = threadIdx.x & 63;
    int q = lane >> 4, i = lane & 15;
    int waveRow = blockIdx.x * 128 + wave * 32;

    bf16x8 a[2][4];
#pragma unroll
    for (int rt = 0; rt < 2; rt++) {
        const ushort* base = &xb[(size_t)(waveRow + rt * 16 + i) * D + q * 8];
#pragma unroll
        for (int ks = 0; ks < 4; ks++)
            a[rt][ks] = *(const bf16x8*)(base + ks * 32);
    }

    f32x4 acc[2][8] = {};
#pragma unroll
    for (int ct = 0; ct < 8; ct++) {
        const ushort* wbase = &wlds[(ct * 16 + i) * WT_LD + q * 8];
#pragma unroll
        for (int ks = 0; ks < 4; ks++) {
            bf16x8 bfr = *(const bf16x8*)(wbase + ks * 32);
            acc[0][ct] = __builtin_amdgcn_mfma_f32_16x16x32_bf16(a[0][ks], bfr, acc[0][ct], 0, 0, 0);
            acc[1][ct] = __builtin_amdgcn_mfma_f32_16x16x32_bf16(a[1][ks], bfr, acc[1][ct], 0, 0, 0);
        }
    }

#pragma unroll
    for (int rt = 0; rt < 2; rt++)
#pragma unroll
        for (int r4 = 0; r4 < 4; r4++) {
            int row = waveRow + rt * 16 + q * 4 + r4;
            float dv = (row < n) ? dinv[row] : 0.f;   // pad rows -> 0 (ZROW guarantee)
#pragma unroll
            for (int ct = 0; ct < 8; ct++)
                h[(size_t)row * D + ct * 16 + i] = f2b(acc[rt][ct][r4] * dv);
        }
}

// ---------------- fused pull_l + gemm_{l+1} ----------------
// Block = 16 dst nodes. Phase 1 (= R1 pull mode-0): 16 lanes/node, lane owns
// feats [8l,8l+8); 16-edge ZROW-padded bursts; x row = dinv*(self+sum)+bias.
// x-tile -> LDS (pad nodes -> zeros) + bf16 store to xb_out (kept for final sum).
// Phase 2: the block's 4 waves compute h_out[16 x 128] = dinv * (x_tile @ Wn):
// wave w covers cols [32w,32w+32); 8 MFMAs; B-frags streamed from global Wt
// (32 KB, L2-resident). Pad rows get dv=0 -> h_out[ZROW]=0 invariant holds.
__global__ __launch_bounds__(256)
void k_fused(const unsigned* __restrict__ rp, const ushort* __restrict__ meta,
             const ushort* __restrict__ h_in,
             const float* __restrict__ dinv, const float* __restrict__ bias,
             const ushort* __restrict__ Wn,
             ushort* __restrict__ xb_out, ushort* __restrict__ h_out, int n) {
    __shared__ ushort xlds[16 * WT_LD];
    __shared__ float  sdinv[16];
    int tid  = threadIdx.x;
    int nl   = tid >> 4;                  // node-local row 0..15
    int l    = tid & 15;                  // feature group
    int node0 = blockIdx.x * 16;
    int node  = node0 + nl;

    u16x8 w = {0, 0, 0, 0, 0, 0, 0, 0};
    float di = 0.f;
    if (node < n) {
        unsigned pk = rp[node];
        int s   = (int)(pk & 0x1FFFFFu);
        int deg = (int)(pk >> 21);
        const ushort* hl = h_in + (l << 3);

        u32x4 sv = *(const u32x4*)(hl + (size_t)node * D);        // self loop
        di = dinv[node];
        const float4* bp = (const float4*)(bias + (l << 3));
        float4 b0 = bp[0], b1 = bp[1];

        float accL[4], accH[4];
#pragma unroll
        for (int k = 0; k < 4; k++) {
            accL[k] = __uint_as_float(sv[k] << 16);
            accH[k] = __uint_as_float(sv[k] & 0xFFFF0000u);
        }
        for (int j = 0; j < deg; j += 16) {
            u16x8 m0 = *(const u16x8*)&meta[s + j];
            u16x8 m1 = *(const u16x8*)&meta[s + j + 8];
            u32x4 v[16];
#pragma unroll
            for (int u = 0; u < 8; u++) v[u]     = *(const u32x4*)(hl + (size_t)m0[u] * D);
#pragma unroll
            for (int u = 0; u < 8; u++) v[8 + u] = *(const u32x4*)(hl + (size_t)m1[u] * D);
#pragma unroll
            for (int u = 0; u < 16; u++)
#pragma unroll
                for (int k = 0; k < 4; k++) {
                    accL[k] += __uint_as_float(v[u][k] << 16);
                    accH[k] += __uint_as_float(v[u][k] & 0xFFFF0000u);
                }
        }
        w[0] = f2b(fmaf(accL[0], di, b0.x));
        w[1] = f2b(fmaf(accH[0], di, b0.y));
        w[2] = f2b(fmaf(accL[1], di, b0.z));
        w[3] = f2b(fmaf(accH[1], di, b0.w));
        w[4] = f2b(fmaf(accL[2], di, b1.x));
        w[5] = f2b(fmaf(accH[2], di, b1.y));
        w[6] = f2b(fmaf(accL[3], di, b1.z));
        w[7] = f2b(fmaf(accH[3], di, b1.w));
        *(u16x8*)(xb_out + (size_t)node * D + (l << 3)) = w;      // kept for final sum
    }
    *(u16x8*)&xlds[nl * WT_LD + l * 8] = w;                        // pad nodes: zeros
    if (l == 0) sdinv[nl] = di;                                    // pad nodes: 0
    __syncthreads();

    // ---- phase 2: 16x128 gemm for the next layer ----
    int wave = tid >> 6, lane = tid & 63;
    int q = lane >> 4, i = lane & 15;

    bf16x8 a[4];
#pragma unroll
    for (int ks = 0; ks < 4; ks++)
        a[ks] = *(const bf16x8*)&xlds[i * WT_LD + ks * 32 + q * 8];

    f32x4 acc[2] = {};
#pragma unroll
    for (int ct = 0; ct < 2; ct++) {
        const ushort* wbase = &Wn[(size_t)(wave * 32 + ct * 16 + i) * D + q * 8];
#pragma unroll
        for (int ks = 0; ks < 4; ks++) {
            bf16x8 bfr = *(const bf16x8*)(wbase + ks * 32);
            acc[ct] = __builtin_amdgcn_mfma_f32_16x16x32_bf16(a[ks], bfr, acc[ct], 0, 0, 0);
        }
    }

#pragma unroll
    for (int r4 = 0; r4 < 4; r4++) {
        int rr = q * 4 + r4;
        float dv = sdinv[rr];                          // 0 for pad rows
#pragma unroll
        for (int ct = 0; ct < 2; ct++)
            h_out[(size_t)(node0 + rr) * D + wave * 32 + ct * 16 + i] =
                f2b(acc[ct][r4] * dv);
    }
}

// ---------------- final pull (mode 1): out = emb + x1 + x2 + x3 ----------------
__global__ __launch_bounds__(256)
void k_pull_final(const unsigned* __restrict__ rp, const ushort* __restrict__ meta,
                  const ushort* __restrict__ h,
                  const float* __restrict__ dinv, const float* __restrict__ bias,
                  const float* __restrict__ emb, const ushort* __restrict__ x1,
                  const ushort* __restrict__ x2, float* __restrict__ out, int n) {
    int node = blockIdx.x * 16 + (threadIdx.x >> 4);
    int l    = threadIdx.x & 15;
    if (node >= n) return;
    unsigned pk = rp[node];
    int s   = (int)(pk & 0x1FFFFFu);
    int deg = (int)(pk >> 21);
    size_t o = (size_t)node * D + (l << 3);
    const ushort* hl = h + (l << 3);

    // early issue: epilogue streams ride under gather latency
    u32x4 sv = *(const u32x4*)(hl + (size_t)node * D);            // self loop
    float di = dinv[node];
    const float4* bp = (const float4*)(bias + (l << 3));
    float4 b0 = bp[0], b1 = bp[1];
    const float4* ep = (const float4*)(emb + o);
    float4 e0 = ep[0], e1 = ep[1];
    u16x8 w1 = *(const u16x8*)(x1 + o);
    u16x8 w2 = *(const u16x8*)(x2 + o);

    float accL[4], accH[4];
#pragma unroll
    for (int k = 0; k < 4; k++) {
        accL[k] = __uint_as_float(sv[k] << 16);
        accH[k] = __uint_as_float(sv[k] & 0xFFFF0000u);
    }
    for (int j = 0; j < deg; j += 16) {
        u16x8 m0 = *(const u16x8*)&meta[s + j];
        u16x8 m1 = *(const u16x8*)&meta[s + j + 8];
        u32x4 v[16];
#pragma unroll
        for (int u = 0; u < 8; u++) v[u]     = *(const u32x4*)(hl + (size_t)m0[u] * D);
#pragma unroll
        for (int u = 0; u < 8; u++) v[8 + u] = *(const u32x4*)(hl + (size_t)m1[u] * D);
#pragma unroll
        for (int u = 0; u < 16; u++)
#pragma unroll
            for (int k = 0; k < 4; k++) {
                accL[k] += __uint_as_float(v[u][k] << 16);
                accH[k] += __uint_as_float(v[u][k] & 0xFFFF0000u);
            }
    }
    f32x4 o0, o1;
    o0[0] = e0.x + b2f(w1[0]) + b2f(w2[0]) + fmaf(accL[0], di, b0.x);
    o0[1] = e0.y + b2f(w1[1]) + b2f(w2[1]) + fmaf(accH[0], di, b0.y);
    o0[2] = e0.z + b2f(w1[2]) + b2f(w2[2]) + fmaf(accL[1], di, b0.z);
    o0[3] = e0.w + b2f(w1[3]) + b2f(w2[3]) + fmaf(accH[1], di, b0.w);
    o1[0] = e1.x + b2f(w1[4]) + b2f(w2[4]) + fmaf(accL[2], di, b1.x);
    o1[1] = e1.y + b2f(w1[5]) + b2f(w2[5]) + fmaf(accH[2], di, b1.y);
    o1[2] = e1.z + b2f(w1[6]) + b2f(w2[6]) + fmaf(accL[3], di, b1.z);
    o1[3] = e1.w + b2f(w1[7]) + b2f(w2[7]) + fmaf(accH[3], di, b1.w);
    __builtin_nontemporal_store(o0, (f32x4*)(out + o));
    __builtin_nontemporal_store(o1, (f32x4*)(out + o) + 1);
}

extern "C" void kernel_launch(void* const* d_in, const int* in_sizes, int n_in,
                              void* d_out, int out_size, void* d_ws, size_t ws_size,
                              hipStream_t stream) {
    const int*   edge = (const int*)d_in[0];    // [2, E]
    const float* emb  = (const float*)d_in[1];  // [100001, 128]
    const float* W    = (const float*)d_in[2];  // [3, 128, 128]
    const float* b    = (const float*)d_in[3];  // [3, 128]
    float* out = (float*)d_out;                 // [50001, 128] fp32

    const int E = in_sizes[0] / 2;
    const int n = NN;
    const int* row = edge;
    const int* col = edge + E;

    char* ws = (char*)d_ws;
    size_t off = 0;
    auto carve = [&](size_t bytes) { char* p = ws + off; off = (off + bytes + 511) / 512 * 512; return p; };
    int*      partCur = (int*)     carve(256 * 4);
    unsigned* part    = (unsigned*)carve((size_t)NBK * CAP * 4);   // 6.0 MB
    ushort*   meta    = (ushort*)  carve((size_t)NBK * CAP * 2);   // 3.0 MB
    unsigned* rp      = (unsigned*)carve((size_t)n * 4);
    float*    dinv    = (float*)   carve((size_t)n * 4);
    ushort*   Wt      = (ushort*)  carve((size_t)3 * D * D * 2);
    ushort*   xb0     = (ushort*)  carve((size_t)NPAD * D * 2);
    ushort*   xb1     = (ushort*)  carve((size_t)NPAD * D * 2);
    ushort*   xb2     = (ushort*)  carve((size_t)NPAD * D * 2);
    ushort*   hA      = (ushort*)  carve((size_t)NPAD * D * 2);
    ushort*   hB      = (ushort*)  carve((size_t)NPAD * D * 2);

    // one small memset; everything else initialized by kernels
    (void)hipMemsetAsync(partCur, 0, 256 * 4, stream);

    const int init_blocks  = (NPAD * (D / 4) + 255) / 256;   // 6256
    const int build_blocks = NBK + 192 + init_blocks;        // 6644
    k_build<<<build_blocks, 256, 0, stream>>>(row, col, partCur, part, W, Wt, emb, xb0, E, n);
    k_scat <<<NBK, 256, 0, stream>>>(part, partCur, dinv, rp, meta, n);

    const int gemm_blocks  = NPAD / 128;         // 391
    const int fused_blocks = NPAD / 16;          // 3128 (covers pad rows -> h_out zeros)
    const int final_blocks = (n + 15) / 16;      // 3126

    // layer 0 gemm: xb0 @ W0 -> hA
    k_gemm_mfma<<<gemm_blocks, 256, 0, stream>>>(xb0, Wt, dinv, hA, n);
    // F1: pull(hA)+bias0 -> x1 (xb1);  x1 @ W1 -> hB
    k_fused<<<fused_blocks, 256, 0, stream>>>(rp, meta, hA, dinv, b,
                                              Wt + (size_t)1 * D * D, xb1, hB, n);
    // F2: pull(hB)+bias1 -> x2 (xb2);  x2 @ W2 -> hA
    k_fused<<<fused_blocks, 256, 0, stream>>>(rp, meta, hB, dinv, b + D,
                                              Wt + (size_t)2 * D * D, xb2, hA, n);
    // final: out = emb + x1 + x2 + (pull(hA)+bias2)
    k_pull_final<<<final_blocks, 256, 0, stream>>>(rp, meta, hA, dinv, b + 2 * D,
                                                   emb, xb1, xb2, out, n);
}